// Round 2
// baseline (939.051 us; speedup 1.0000x reference)
//
#include <hip/hip_runtime.h>
#include <math.h>

// Problem constants (match reference file)
constexpr int   NSEG     = 100000;
constexpr int   D        = 64;
constexpr float INV_TEMP = 1.0f / 8.0f;   // 1/TEMPERATURE
constexpr int   CAP      = 256;           // per-wave LDS score capacity

// ---------------------------------------------------------------------------
// Pass 1: offsets[s] = first edge e with index[e] >= s   (index is sorted).
// Each offsets entry in [0, NSEG] is written exactly once per call.
// ---------------------------------------------------------------------------
__global__ void build_offsets_kernel(const int* __restrict__ index,
                                     int* __restrict__ offsets,
                                     int E, int nseg) {
    int e = blockIdx.x * blockDim.x + threadIdx.x;
    if (e >= E) return;
    int cur = index[e];
    if (e == 0) {
        for (int s = 0; s <= cur; ++s) offsets[s] = 0;
    } else {
        int prev = index[e - 1];
        for (int s = prev + 1; s <= cur; ++s) offsets[s] = e;
    }
    if (e == E - 1) {
        for (int s = cur + 1; s <= nseg; ++s) offsets[s] = E;
    }
}

// ---------------------------------------------------------------------------
// Pass 2: fused dot-product + segment softmax. One wave (64 lanes) per
// segment. 4 edges per iteration: 16 lanes x float4 cover one D=64 row.
// Scores cached in LDS (len <= CAP fast path); general recompute fallback.
// Waves are independent -> no __syncthreads, no divergent-barrier hazard.
// ---------------------------------------------------------------------------
__global__ __launch_bounds__(256) void seg_softmax_kernel(
        const float* __restrict__ q,
        const float* __restrict__ k,
        const int* __restrict__ offsets,
        float* __restrict__ out,
        int nseg) {
    const int lane = threadIdx.x & 63;
    const int wid  = threadIdx.x >> 6;          // wave within block (0..3)
    const int seg  = blockIdx.x * 4 + wid;

    __shared__ float lds_scores[4][CAP];

    if (seg >= nseg) return;
    const int start = offsets[seg];
    const int end   = offsets[seg + 1];
    const int len   = end - start;
    if (len <= 0) return;                       // empty segment: nothing to write

    const int sub = lane >> 4;                  // which of 4 edges this lane helps
    const int t16 = lane & 15;                  // float4 slot within the row
    float* __restrict__ srow = lds_scores[wid];

    if (len <= CAP) {
        // ---- pass A: scores -> LDS, running max in registers ----
        float m = -INFINITY;
        for (int base = start; base < end; base += 4) {
            const int e = base + sub;
            float sc = 0.0f;
            if (e < end) {
                const float4 qv = *((const float4*)(q + (long)e * D) + t16);
                const float4 kv = *((const float4*)(k + (long)e * D) + t16);
                sc = qv.x * kv.x + qv.y * kv.y + qv.z * kv.z + qv.w * kv.w;
            }
            // sum across the 16 lanes of this edge's group
            sc += __shfl_xor(sc, 1);
            sc += __shfl_xor(sc, 2);
            sc += __shfl_xor(sc, 4);
            sc += __shfl_xor(sc, 8);
            sc *= INV_TEMP;
            if (e < end) {
                m = fmaxf(m, sc);
                if (t16 == 0) srow[e - start] = sc;
            }
        }
        // max across the 4 sub-groups
        m = fmaxf(m, __shfl_xor(m, 16));
        m = fmaxf(m, __shfl_xor(m, 32));
        __builtin_amdgcn_wave_barrier();  // pin LDS write->read program order

        // ---- pass B: sum of exp; cache exp back into LDS for pass C ----
        float l = 0.0f;
        for (int i = lane; i < len; i += 64) {
            const float ex = __expf(srow[i] - m);
            srow[i] = ex;
            l += ex;
        }
        #pragma unroll
        for (int msk = 1; msk < 64; msk <<= 1) l += __shfl_xor(l, msk);
        const float invl = 1.0f / l;

        // ---- pass C: normalized output, coalesced ----
        for (int i = lane; i < len; i += 64)
            out[start + i] = srow[i] * invl;
    } else {
        // ---- general fallback (len > CAP): 3 passes, recompute scores ----
        float m = -INFINITY;
        for (int base = start; base < end; base += 4) {
            const int e = base + sub;
            float sc = 0.0f;
            if (e < end) {
                const float4 qv = *((const float4*)(q + (long)e * D) + t16);
                const float4 kv = *((const float4*)(k + (long)e * D) + t16);
                sc = qv.x * kv.x + qv.y * kv.y + qv.z * kv.z + qv.w * kv.w;
            }
            sc += __shfl_xor(sc, 1);
            sc += __shfl_xor(sc, 2);
            sc += __shfl_xor(sc, 4);
            sc += __shfl_xor(sc, 8);
            sc *= INV_TEMP;
            if (e < end) m = fmaxf(m, sc);
        }
        m = fmaxf(m, __shfl_xor(m, 16));
        m = fmaxf(m, __shfl_xor(m, 32));

        float l = 0.0f;  // each edge counted 16x (all group lanes), fixed below
        for (int base = start; base < end; base += 4) {
            const int e = base + sub;
            float sc = 0.0f;
            if (e < end) {
                const float4 qv = *((const float4*)(q + (long)e * D) + t16);
                const float4 kv = *((const float4*)(k + (long)e * D) + t16);
                sc = qv.x * kv.x + qv.y * kv.y + qv.z * kv.z + qv.w * kv.w;
            }
            sc += __shfl_xor(sc, 1);
            sc += __shfl_xor(sc, 2);
            sc += __shfl_xor(sc, 4);
            sc += __shfl_xor(sc, 8);
            sc *= INV_TEMP;
            if (e < end) l += __expf(sc - m);
        }
        #pragma unroll
        for (int msk = 1; msk < 64; msk <<= 1) l += __shfl_xor(l, msk);
        const float invl = 16.0f / l;    // undo the 16x over-count

        for (int base = start; base < end; base += 4) {
            const int e = base + sub;
            float sc = 0.0f;
            if (e < end) {
                const float4 qv = *((const float4*)(q + (long)e * D) + t16);
                const float4 kv = *((const float4*)(k + (long)e * D) + t16);
                sc = qv.x * kv.x + qv.y * kv.y + qv.z * kv.z + qv.w * kv.w;
            }
            sc += __shfl_xor(sc, 1);
            sc += __shfl_xor(sc, 2);
            sc += __shfl_xor(sc, 4);
            sc += __shfl_xor(sc, 8);
            sc *= INV_TEMP;
            if (e < end && t16 == 0) out[e] = __expf(sc - m) * invl;
        }
    }
}

// ---------------------------------------------------------------------------
extern "C" void kernel_launch(void* const* d_in, const int* in_sizes, int n_in,
                              void* d_out, int out_size, void* d_ws, size_t ws_size,
                              hipStream_t stream) {
    const float* q     = (const float*)d_in[0];
    const float* k     = (const float*)d_in[1];
    const int*   index = (const int*)d_in[2];
    float*       out   = (float*)d_out;

    const int E = in_sizes[2];          // number of edges (index element count)
    int* offsets = (int*)d_ws;          // (NSEG + 1) ints of scratch

    {
        dim3 grid((E + 255) / 256), block(256);
        build_offsets_kernel<<<grid, block, 0, stream>>>(index, offsets, E, NSEG);
    }
    {
        dim3 grid((NSEG + 3) / 4), block(256);
        seg_softmax_kernel<<<grid, block, 0, stream>>>(q, k, offsets, out, NSEG);
    }
}